// Round 1
// baseline (45.897 us; speedup 1.0000x reference)
//
#include <hip/hip_runtime.h>
#include <math.h>

#define NN 512
#define D  256   // EMB_DIM == HID
#define TI1 8    // rows per block in gemm kernel
#define TI2 4    // i-rows per block in pair kernel

// Kernel 1: hxb[j,:] = x[j,:] @ W1x + b1 ; hy[i,:] = y[i,:] @ W1y
// W1 is (512,256) row-major: rows 0..255 = W1x, rows 256..511 = W1y.
__global__ __launch_bounds__(256) void gemm_rows(
    const float* __restrict__ x, const float* __restrict__ y,
    const float* __restrict__ W1, const float* __restrict__ b1,
    float* __restrict__ hxb, float* __restrict__ hy)
{
    __shared__ float rowS[TI1][D];
    int b = blockIdx.x;             // 0..127 : first 64 -> x, last 64 -> y
    bool isx = (b < 64);
    const float* src = isx ? x : y;
    float* dst = isx ? hxb : hy;
    int r0 = (b & 63) * TI1;
    const float* Wb = W1 + (isx ? 0 : D * D);
    int t = threadIdx.x;            // 0..255 = output column k

    for (int idx = t; idx < TI1 * D; idx += 256)
        rowS[idx >> 8][idx & 255] = src[r0 * D + idx];
    __syncthreads();

    float acc[TI1];
    float bias = isx ? b1[t] : 0.0f;
#pragma unroll
    for (int i = 0; i < TI1; ++i) acc[i] = bias;

    for (int m = 0; m < D; ++m) {
        float w = Wb[m * D + t];    // coalesced across threads
#pragma unroll
        for (int i = 0; i < TI1; ++i)
            acc[i] = fmaf(rowS[i][m], w, acc[i]);  // rowS broadcast: free
    }
#pragma unroll
    for (int i = 0; i < TI1; ++i)
        dst[(r0 + i) * D + t] = acc[i];
}

// Kernel 2: block b owns i in [4b,4b+4); thread t owns column j=t.
// t1[i][j] = softplus( sum_k relu(hyS[i][k] + hxb[j][k]) * W2[k] + b2 )
// then per-i stable logsumexp over j, plus diagonal T0[i] = t1[i][i].
__global__ __launch_bounds__(512) void pair_kernel(
    const float* __restrict__ hxb, const float* __restrict__ hy,
    const float* __restrict__ W2, const float* __restrict__ b2p,
    float* __restrict__ lse_out, float* __restrict__ t0_out)
{
    __shared__ float hyS[TI2][D];
    __shared__ float w2S[D];
    __shared__ float t1S[TI2][NN];
    __shared__ float red[16];

    int b = blockIdx.x;         // 0..127
    int i0 = b * TI2;
    int t = threadIdx.x;        // 0..511 == j

    for (int idx = t; idx < TI2 * D; idx += 512)
        hyS[idx >> 8][idx & 255] = hy[i0 * D + idx];
    if (t < D) w2S[t] = W2[t];
    __syncthreads();

    float b2 = b2p[0];
    float acc[TI2];
#pragma unroll
    for (int i = 0; i < TI2; ++i) acc[i] = 0.0f;

    const float4* hrow = (const float4*)(hxb + t * D);
    for (int kc = 0; kc < D / 4; ++kc) {
        float4 hv = hrow[kc];   // per-lane own row: 16B/lane, L2-hot
#pragma unroll
        for (int i = 0; i < TI2; ++i) {
            float4 hyv = *(const float4*)(&hyS[i][kc * 4]);  // broadcast b128
            float4 w2v = *(const float4*)(&w2S[kc * 4]);
            acc[i] = fmaf(fmaxf(hyv.x + hv.x, 0.0f), w2v.x, acc[i]);
            acc[i] = fmaf(fmaxf(hyv.y + hv.y, 0.0f), w2v.y, acc[i]);
            acc[i] = fmaf(fmaxf(hyv.z + hv.z, 0.0f), w2v.z, acc[i]);
            acc[i] = fmaf(fmaxf(hyv.w + hv.w, 0.0f), w2v.w, acc[i]);
        }
    }

#pragma unroll
    for (int i = 0; i < TI2; ++i) {
        float z = acc[i] + b2;
        // stable softplus, matches log1p(exp(z))
        float sp = fmaxf(z, 0.0f) + log1pf(expf(-fabsf(z)));
        t1S[i][t] = sp;
    }
    __syncthreads();

    int lane = t & 63, wid = t >> 6;
    for (int i = 0; i < TI2; ++i) {
        float v = t1S[i][t];
        // wave max
        float m = v;
        for (int off = 32; off >= 1; off >>= 1)
            m = fmaxf(m, __shfl_xor(m, off));
        if (lane == 0) red[wid] = m;
        __syncthreads();
        if (t == 0) {
            float mm = red[0];
            for (int w = 1; w < 8; ++w) mm = fmaxf(mm, red[w]);
            red[8] = mm;
        }
        __syncthreads();
        float mm = red[8];
        float e = expf(v - mm);
        for (int off = 32; off >= 1; off >>= 1)
            e += __shfl_xor(e, off);
        if (lane == 0) red[wid] = e;
        __syncthreads();
        if (t == 0) {
            float s = 0.0f;
            for (int w = 0; w < 8; ++w) s += red[w];
            int gi = i0 + i;
            lse_out[gi] = mm + logf(s);
            t0_out[gi] = t1S[i][gi];   // diagonal element = T0[gi]
        }
        __syncthreads();
    }
}

// Kernel 3: out = mean(lse) - log(N) - mean(T0)   (= -lower_bound)
__global__ __launch_bounds__(512) void finalize(
    const float* __restrict__ lse, const float* __restrict__ t0,
    float* __restrict__ out)
{
    __shared__ float redA[8], redB[8];
    int t = threadIdx.x;
    float a = lse[t];
    float bb = t0[t];
    int lane = t & 63, wid = t >> 6;
    for (int off = 32; off >= 1; off >>= 1) {
        a += __shfl_xor(a, off);
        bb += __shfl_xor(bb, off);
    }
    if (lane == 0) { redA[wid] = a; redB[wid] = bb; }
    __syncthreads();
    if (t == 0) {
        float sa = 0.0f, sb = 0.0f;
        for (int w = 0; w < 8; ++w) { sa += redA[w]; sb += redB[w]; }
        out[0] = sa / 512.0f - logf(512.0f) - sb / 512.0f;
    }
}

extern "C" void kernel_launch(void* const* d_in, const int* in_sizes, int n_in,
                              void* d_out, int out_size, void* d_ws, size_t ws_size,
                              hipStream_t stream)
{
    const float* x  = (const float*)d_in[0];
    const float* y  = (const float*)d_in[1];
    const float* W1 = (const float*)d_in[2];
    const float* b1 = (const float*)d_in[3];
    const float* W2 = (const float*)d_in[4];
    const float* b2 = (const float*)d_in[5];
    float* out = (float*)d_out;

    float* ws  = (float*)d_ws;
    float* hxb = ws;                    // 512*256
    float* hy  = ws + NN * D;           // 512*256
    float* lse = ws + 2 * NN * D;       // 512
    float* t0  = lse + NN;              // 512

    gemm_rows<<<128, 256, 0, stream>>>(x, y, W1, b1, hxb, hy);
    pair_kernel<<<NN / TI2, 512, 0, stream>>>(hxb, hy, W2, b2, lse, t0);
    finalize<<<1, 512, 0, stream>>>(lse, t0, out);
}

// Round 2
// 38.648 us; speedup vs baseline: 1.1876x; 1.1876x over previous
//
#include <hip/hip_runtime.h>
#include <math.h>

#define NN 512
#define D  256   // EMB_DIM == HID

// Kernel 1: hxb[j,:] = x[j,:] @ W1x + b1 ; hy[i,:] = y[i,:] @ W1y
// 256 blocks x 256 threads; block b<128 -> 4 rows of x, b>=128 -> 4 rows of y.
// x rows are block-uniform -> scalar (SMEM) loads; W loads coalesced per thread.
__global__ __launch_bounds__(256) void gemm_rows(
    const float* __restrict__ x, const float* __restrict__ y,
    const float* __restrict__ W1, const float* __restrict__ b1,
    float* __restrict__ hxb, float* __restrict__ hy,
    unsigned int* __restrict__ counter)
{
    if (blockIdx.x == 0 && threadIdx.x == 0) *counter = 0u;  // reset for kernel 2

    int b = blockIdx.x;
    bool isx = (b < 128);
    const float* src = isx ? x : y;
    float* dst = isx ? hxb : hy;
    int r0 = (b & 127) * 4;
    const float* Wb = W1 + (isx ? 0 : D * D);
    int t = threadIdx.x;            // output column k

    float bias = isx ? b1[t] : 0.0f;
    float a0 = bias, a1 = bias, a2 = bias, a3 = bias;

    const float4* s0 = (const float4*)(src + (r0 + 0) * D);
    const float4* s1 = (const float4*)(src + (r0 + 1) * D);
    const float4* s2 = (const float4*)(src + (r0 + 2) * D);
    const float4* s3 = (const float4*)(src + (r0 + 3) * D);

    for (int m4 = 0; m4 < D / 4; ++m4) {
        float4 v0 = s0[m4], v1 = s1[m4], v2 = s2[m4], v3 = s3[m4]; // uniform -> s_load_dwordx4
        const float* Wc = Wb + (m4 * 4) * D + t;
        float w0 = Wc[0], w1 = Wc[D], w2 = Wc[2 * D], w3 = Wc[3 * D]; // coalesced
        a0 = fmaf(v0.x, w0, a0); a0 = fmaf(v0.y, w1, a0); a0 = fmaf(v0.z, w2, a0); a0 = fmaf(v0.w, w3, a0);
        a1 = fmaf(v1.x, w0, a1); a1 = fmaf(v1.y, w1, a1); a1 = fmaf(v1.z, w2, a1); a1 = fmaf(v1.w, w3, a1);
        a2 = fmaf(v2.x, w0, a2); a2 = fmaf(v2.y, w1, a2); a2 = fmaf(v2.z, w2, a2); a2 = fmaf(v2.w, w3, a2);
        a3 = fmaf(v3.x, w0, a3); a3 = fmaf(v3.y, w1, a3); a3 = fmaf(v3.z, w2, a3); a3 = fmaf(v3.w, w3, a3);
    }
    dst[(r0 + 0) * D + t] = a0;
    dst[(r0 + 1) * D + t] = a1;
    dst[(r0 + 2) * D + t] = a2;
    dst[(r0 + 3) * D + t] = a3;
}

// Kernel 2: block b owns i = {2b, 2b+1}; thread t owns column j = t.
// z[i][j] = sum_k relu(hy[i,k] + hxb[j,k]) * W2[k] + b2
// exp(softplus(z)) == 1 + exp(z), so lse_i = log(512 + sum_j exp(z_ij)).
// Diagonal T0[i] = softplus(z[i,i]). Deterministic last-block finalize.
__global__ __launch_bounds__(512) void pair_kernel(
    const float* __restrict__ hxb, const float* __restrict__ hy,
    const float* __restrict__ W2, const float* __restrict__ b2p,
    float* __restrict__ partials, unsigned int* __restrict__ counter,
    float* __restrict__ out)
{
    int b = blockIdx.x;         // 0..255
    int i0 = b * 2;
    int t = threadIdx.x;        // 0..511 == j

    float acc0 = 0.0f, acc1 = 0.0f;
    const float4* hrow = (const float4*)(hxb + t * D);          // per-thread row
    const float4* hyr0 = (const float4*)(hy + (i0 + 0) * D);    // uniform -> s_load
    const float4* hyr1 = (const float4*)(hy + (i0 + 1) * D);    // uniform -> s_load
    const float4* w2p  = (const float4*)W2;                     // uniform -> s_load

    for (int kc = 0; kc < D / 4; ++kc) {
        float4 hv = hrow[kc];
        float4 a  = hyr0[kc];
        float4 c  = hyr1[kc];
        float4 w  = w2p[kc];
        acc0 = fmaf(fmaxf(a.x + hv.x, 0.0f), w.x, acc0);
        acc0 = fmaf(fmaxf(a.y + hv.y, 0.0f), w.y, acc0);
        acc0 = fmaf(fmaxf(a.z + hv.z, 0.0f), w.z, acc0);
        acc0 = fmaf(fmaxf(a.w + hv.w, 0.0f), w.w, acc0);
        acc1 = fmaf(fmaxf(c.x + hv.x, 0.0f), w.x, acc1);
        acc1 = fmaf(fmaxf(c.y + hv.y, 0.0f), w.y, acc1);
        acc1 = fmaf(fmaxf(c.z + hv.z, 0.0f), w.z, acc1);
        acc1 = fmaf(fmaxf(c.w + hv.w, 0.0f), w.w, acc1);
    }

    float b2 = b2p[0];
    float z0 = acc0 + b2, z1 = acc1 + b2;
    float e0 = expf(z0), e1 = expf(z1);    // exp(softplus(z)) = 1 + e^z; "+1" added later

    __shared__ float ws0[8], ws1[8], diagS[2];
    __shared__ int islastS;
    int lane = t & 63, wid = t >> 6;

    if (t == i0)     diagS[0] = fmaxf(z0, 0.0f) + log1pf(expf(-fabsf(z0)));
    if (t == i0 + 1) diagS[1] = fmaxf(z1, 0.0f) + log1pf(expf(-fabsf(z1)));

    float s0 = e0, s1 = e1;
#pragma unroll
    for (int off = 32; off >= 1; off >>= 1) {
        s0 += __shfl_xor(s0, off);
        s1 += __shfl_xor(s1, off);
    }
    if (lane == 0) { ws0[wid] = s0; ws1[wid] = s1; }
    __syncthreads();

    if (t == 0) {
        float tot0 = 512.0f, tot1 = 512.0f;   // the "+1" of each of 512 j's
#pragma unroll
        for (int w = 0; w < 8; ++w) { tot0 += ws0[w]; tot1 += ws1[w]; }
        float lse0 = logf(tot0), lse1 = logf(tot1);
        float part = (lse0 - diagS[0] + lse1 - diagS[1]) * (1.0f / 512.0f);
        if (b == 0) part -= logf(512.0f);
        __hip_atomic_store(&partials[b], part, __ATOMIC_RELEASE, __HIP_MEMORY_SCOPE_AGENT);
        unsigned prev = __hip_atomic_fetch_add(counter, 1u, __ATOMIC_ACQ_REL, __HIP_MEMORY_SCOPE_AGENT);
        islastS = (prev == 255u) ? 1 : 0;
    }
    __syncthreads();

    // Last block to finish reduces all 256 partials in a FIXED order -> deterministic.
    if (islastS && t < 64) {
        float s = 0.0f;
#pragma unroll
        for (int q = 0; q < 4; ++q)
            s += __hip_atomic_load(&partials[t + 64 * q], __ATOMIC_ACQUIRE, __HIP_MEMORY_SCOPE_AGENT);
#pragma unroll
        for (int off = 32; off >= 1; off >>= 1) s += __shfl_xor(s, off);
        if (t == 0) out[0] = s;   // = mean(lse) - log N - mean(T0)
    }
}

extern "C" void kernel_launch(void* const* d_in, const int* in_sizes, int n_in,
                              void* d_out, int out_size, void* d_ws, size_t ws_size,
                              hipStream_t stream)
{
    const float* x  = (const float*)d_in[0];
    const float* y  = (const float*)d_in[1];
    const float* W1 = (const float*)d_in[2];
    const float* b1 = (const float*)d_in[3];
    const float* W2 = (const float*)d_in[4];
    const float* b2 = (const float*)d_in[5];
    float* out = (float*)d_out;

    float* ws  = (float*)d_ws;
    float* hxb = ws;                         // 512*256
    float* hy  = ws + NN * D;                // 512*256
    float* partials = ws + 2 * NN * D;       // 256
    unsigned int* counter = (unsigned int*)(ws + 2 * NN * D + 256);

    gemm_rows<<<256, 256, 0, stream>>>(x, y, W1, b1, hxb, hy, counter);
    pair_kernel<<<256, 512, 0, stream>>>(hxb, hy, W2, b2, partials, counter, out);
}